// Round 1
// baseline (474.046 us; speedup 1.0000x reference)
//
#include <hip/hip_runtime.h>

// Input:  image [D0=256][D1=384][D2=384] fp32
// Output: out   [S1=384][S0=320][S2=512] fp32  (leading singleton dim dropped)
//
// out[j][i][k] = (1-w0) * ( in[a0][j][b0]*(1-w2) + in[a0][j][b1]*w2 )
//              +   w0  * ( in[a1][j][b0]*(1-w2) + in[a1][j][b1]*w2 )
// with half-pixel, align_corners=False source coords (PyTorch semantics).

#define D0 256
#define D1 384
#define D2 384
#define S0 320
#define S1 384
#define S2 512

__global__ __launch_bounds__(128) void resize3d_kernel(
    const float* __restrict__ in, float* __restrict__ out)
{
    const int b = blockIdx.x;        // b = j * S0 + i
    const int i = b % S0;
    const int j = b / S0;
    const int t = threadIdx.x;       // 0..127, each thread does 4 consecutive k

    // axis-0 interp params (256 -> 320), scale = 0.8f
    const float scale0 = (float)D0 / (float)S0;
    float src0 = fmaxf((i + 0.5f) * scale0 - 0.5f, 0.0f);
    int   a0   = (int)src0;          // floor, src0 >= 0
    float w0   = src0 - (float)a0;
    int   a1   = min(a0 + 1, D0 - 1);

    const float* __restrict__ row0 = in + ((size_t)a0 * D1 + j) * D2;
    const float* __restrict__ row1 = in + ((size_t)a1 * D1 + j) * D2;

    const float scale2 = (float)D2 / (float)S2;   // 0.75f exactly
    const int kbase = t * 4;

    float4 res;
    float* rp = &res.x;
#pragma unroll
    for (int q = 0; q < 4; ++q) {
        int   k    = kbase + q;
        float src2 = fmaxf((k + 0.5f) * scale2 - 0.5f, 0.0f);
        int   b0   = (int)src2;
        float w2   = src2 - (float)b0;
        int   b1   = min(b0 + 1, D2 - 1);
        // match reference nesting: k-interp first (pass 1), then i-interp (pass 2)
        float t0 = row0[b0] * (1.0f - w2) + row0[b1] * w2;
        float t1 = row1[b0] * (1.0f - w2) + row1[b1] * w2;
        rp[q] = t0 * (1.0f - w0) + t1 * w0;
    }

    reinterpret_cast<float4*>(out)[(size_t)b * (S2 / 4) + t] = res;
}

extern "C" void kernel_launch(void* const* d_in, const int* in_sizes, int n_in,
                              void* d_out, int out_size, void* d_ws, size_t ws_size,
                              hipStream_t stream)
{
    const float* in  = (const float*)d_in[0];
    float*       out = (float*)d_out;

    dim3 grid(S1 * S0);   // 122880 blocks: b = j*S0 + i (j-major for L2 locality)
    dim3 block(128);
    resize3d_kernel<<<grid, block, 0, stream>>>(in, out);
}

// Round 2
// 356.052 us; speedup vs baseline: 1.3314x; 1.3314x over previous
//
#include <hip/hip_runtime.h>

// Input:  image [D0=256][D1=384][D2=384] fp32
// Output: out   [S1=384][S0=320][S2=512] fp32  (leading singleton dim dropped)
//
// out[j][i][k] = (1-w0) * ( in[a0][j][b0]*(1-w2) + in[a0][j][b1]*w2 )
//              +   w0  * ( in[a1][j][b0]*(1-w2) + in[a1][j][b1]*w2 )
// half-pixel, align_corners=False (PyTorch semantics). Axis-1 resize is an
// exact identity (384->384), second-pass axis-2 is identity (512->512).

#define D0 256
#define D1 384
#define D2 384
#define S0 320
#define S1 384
#define S2 512

__global__ __launch_bounds__(128) void resize3d_kernel(
    const float* __restrict__ in, float* __restrict__ out)
{
    // Stage the two source rows in LDS: scattered interp reads hit LDS, not L1.
    __shared__ float r0[D2];
    __shared__ float r1[D2];

    const int b = blockIdx.x;        // b = j * S0 + i  (j-major: per-j input set stays L2-hot)
    const int i = b % S0;
    const int j = b / S0;
    const int t = threadIdx.x;       // 0..127

    // axis-0 interp params (256 -> 320), scale = 0.8
    const float scale0 = (float)D0 / (float)S0;
    float src0 = fmaxf((i + 0.5f) * scale0 - 0.5f, 0.0f);
    int   a0   = (int)src0;          // floor, src0 >= 0
    float w0   = src0 - (float)a0;
    int   a1   = min(a0 + 1, D0 - 1);

    const float* __restrict__ row0 = in + ((size_t)a0 * D1 + j) * D2;
    const float* __restrict__ row1 = in + ((size_t)a1 * D1 + j) * D2;

    // Coalesced stage: lane-consecutive 4B loads (256 B per wave per inst).
#pragma unroll
    for (int p = 0; p < D2 / 128; ++p) {
        int idx = t + p * 128;
        r0[idx] = row0[idx];
        r1[idx] = row1[idx];
    }
    __syncthreads();

    const float scale2 = (float)D2 / (float)S2;   // 0.75 exactly
    const int kbase = t * 4;

    float4 res;
    float* rp = &res.x;
#pragma unroll
    for (int q = 0; q < 4; ++q) {
        int   k    = kbase + q;
        float src2 = fmaxf((k + 0.5f) * scale2 - 0.5f, 0.0f);
        int   b0   = (int)src2;
        float w2   = src2 - (float)b0;
        int   b1   = min(b0 + 1, D2 - 1);
        // match reference nesting: k-interp first (pass 1), then i-interp (pass 2)
        float t0 = r0[b0] * (1.0f - w2) + r0[b1] * w2;   // LDS: stride-3 lanes, conflict-free
        float t1 = r1[b0] * (1.0f - w2) + r1[b1] * w2;
        rp[q] = t0 * (1.0f - w0) + t1 * w0;
    }

    reinterpret_cast<float4*>(out)[(size_t)b * (S2 / 4) + t] = res;
}

extern "C" void kernel_launch(void* const* d_in, const int* in_sizes, int n_in,
                              void* d_out, int out_size, void* d_ws, size_t ws_size,
                              hipStream_t stream)
{
    const float* in  = (const float*)d_in[0];
    float*       out = (float*)d_out;

    dim3 grid(S1 * S0);   // 122880 blocks: b = j*S0 + i
    dim3 block(128);
    resize3d_kernel<<<grid, block, 0, stream>>>(in, out);
}

// Round 3
// 350.970 us; speedup vs baseline: 1.3507x; 1.0145x over previous
//
#include <hip/hip_runtime.h>

// Input:  image [D0=256][D1=384][D2=384] fp32
// Output: out   [S1=384][S0=320][S2=512] fp32
//
// out[j][i][k] = (1-w0)*( in[a0][j][b0]*(1-w2) + in[a0][j][b1]*w2 )
//              +   w0 *( in[a1][j][b0]*(1-w2) + in[a1][j][b1]*w2 )
// half-pixel, align_corners=False. Axis-1 (384->384) and second-pass axis-2
// (512->512) are exact identities.
//
// Structure: one block = (j, tile of 8 output rows i0..i0+7). The 8 outputs
// need source rows base..base+7 only (span 7*0.8=5.6 +1). Stage them in LDS
// via float4 loads; axis-2 uses the exact 3:4 ratio: output quad m reads
// source cols {3m-1,3m,3m+1,3m+2,3m+3} with constant weights.

#define D0 256
#define D1 384
#define D2 384
#define S0 320
#define S1 384
#define S2 512
#define TI 8            // output rows per block
#define NT 256          // threads per block

__global__ __launch_bounds__(NT) void resize3d_kernel(
    const float* __restrict__ in, float* __restrict__ out)
{
    __shared__ float rows[TI][D2];   // 12 KB

    const int blk  = blockIdx.x;             // blk = j * (S0/TI) + tile
    const int tile = blk % (S0 / TI);
    const int j    = blk / (S0 / TI);
    const int tid  = threadIdx.x;

    const int   i0     = tile * TI;
    const float scale0 = (float)D0 / (float)S0;   // 0.8
    const int   base   = (int)fmaxf((i0 + 0.5f) * scale0 - 0.5f, 0.0f);

    // ---- stage TI rows, fully coalesced dwordx4: 768 float4, 3 per thread ----
#pragma unroll
    for (int wv = 0; wv < (TI * (D2 / 4)) / NT; ++wv) {
        int s = tid + wv * NT;
        int r = s / (D2 / 4);
        int c = s % (D2 / 4);
        int g = min(base + r, D0 - 1);
        const float4* gp =
            reinterpret_cast<const float4*>(in + ((size_t)g * D1 + j) * D2);
        *reinterpret_cast<float4*>(&rows[r][4 * c]) = gp[c];
    }
    __syncthreads();

    const int oc     = tid & 127;   // float4 column: outputs k = 4*oc+q
    const int orbase = tid >> 7;    // 0/1; thread handles output rows orbase+2p

    // axis-2 source cols for quad oc (weights are exact constants)
    const int m3 = 3 * oc;
    const int c0 = max(m3 - 1, 0);          // oc=0 edge: clamp (w2=0 case, dup-safe)
    const int c4 = min(m3 + 3, D2 - 1);     // oc=127 edge: b1 clamp

#pragma unroll
    for (int p = 0; p < 4; ++p) {
        int   orow = orbase + 2 * p;        // 0..7
        int   i    = i0 + orow;
        float src0 = fmaxf((i + 0.5f) * scale0 - 0.5f, 0.0f);
        int   a0   = (int)src0;
        float w0   = src0 - (float)a0;
        int   l0   = a0 - base;
        int   l1   = min(a0 + 1, D0 - 1) - base;

        const float* __restrict__ r0 = rows[l0];
        const float* __restrict__ r1 = rows[l1];
        // stride-3 lanes -> conflict-free LDS reads
        float u0 = r0[c0], u1 = r0[m3], u2 = r0[m3 + 1], u3 = r0[m3 + 2], u4 = r0[c4];
        float v0 = r1[c0], v1 = r1[m3], v2 = r1[m3 + 1], v3 = r1[m3 + 2], v4 = r1[c4];

        // pass-1 (k) interp with constant weights, matching reference formula
        float t0q0 = u0 * 0.125f + u1 * 0.875f;
        float t0q1 = u1 * 0.375f + u2 * 0.625f;
        float t0q2 = u2 * 0.625f + u3 * 0.375f;
        float t0q3 = u3 * 0.875f + u4 * 0.125f;
        float t1q0 = v0 * 0.125f + v1 * 0.875f;
        float t1q1 = v1 * 0.375f + v2 * 0.625f;
        float t1q2 = v2 * 0.625f + v3 * 0.375f;
        float t1q3 = v3 * 0.875f + v4 * 0.125f;

        // pass-2 (i) interp
        float iw = 1.0f - w0;
        float4 res;
        res.x = t0q0 * iw + t1q0 * w0;
        res.y = t0q1 * iw + t1q1 * w0;
        res.z = t0q2 * iw + t1q2 * w0;
        res.w = t0q3 * iw + t1q3 * w0;

        reinterpret_cast<float4*>(out)[((size_t)j * S0 + i) * (S2 / 4) + oc] = res;
    }
}

extern "C" void kernel_launch(void* const* d_in, const int* in_sizes, int n_in,
                              void* d_out, int out_size, void* d_ws, size_t ws_size,
                              hipStream_t stream)
{
    const float* in  = (const float*)d_in[0];
    float*       out = (float*)d_out;

    dim3 grid(S1 * (S0 / TI));   // 384 * 40 = 15360 blocks
    dim3 block(NT);
    resize3d_kernel<<<grid, block, 0, stream>>>(in, out);
}